// Round 4
// baseline (120.605 us; speedup 1.0000x reference)
//
#include <hip/hip_runtime.h>
#include <math.h>

#define BB 64
#define TT 2048
#define DD 512
#define TCH 32            // chunks per batch row
#define TC (TT / TCH)     // 64 t per chunk

// ---------------------------------------------------------------------------
// Kernel 1 (one-pass flash chunk): block = (b, tc), 256 threads = 4 waves.
// Phase A: energy for 64 rows (wave-per-row dot, shuffle reduce) -> LDS
// Phase B: local softmax stats m_c, s_c; w = exp(e - m_c) -> LDS + ws
// Phase C: acc = sum_t w[t] * V[b,t,:]  (thread owns float2 at d2 = tid)
// No cross-block communication (round-2 lesson: fences serialize the TCC).
// ---------------------------------------------------------------------------
__global__ __launch_bounds__(256) void fused_chunk(
    const float* __restrict__ q, const float* __restrict__ k,
    const float* __restrict__ v, const int* __restrict__ mask,
    float* __restrict__ wbuf,     // [B,T]  exp(e - m_c)
    float* __restrict__ partial,  // [B,TCH,D]
    float* __restrict__ mstat,    // [B,TCH]
    float* __restrict__ sstat) {  // [B,TCH]
  const int b = blockIdx.x;
  const int tc = blockIdx.y;
  const int tid = threadIdx.x;
  const int wave = tid >> 6;
  const int lane = tid & 63;

  __shared__ float se[TC];  // raw energies
  __shared__ float sw[TC];  // exp weights

  const int t0 = tc * TC;
  const long long base = ((long long)b * TT + t0) * DD;

  // ---- Phase A: energies (each wave: 16 rows, coalesced 2KB row reads)
  const float4* qp4 = (const float4*)(q + b * DD);
  const float4 qa = qp4[lane];
  const float4 qb = qp4[lane + 64];

#pragma unroll 2
  for (int i = 0; i < TC / 4; ++i) {
    const int r = wave * (TC / 4) + i;
    const float4* kp4 = (const float4*)(k + base + (long long)r * DD);
    const float4 ka = kp4[lane];
    const float4 kb = kp4[lane + 64];
    float s = ka.x * qa.x + ka.y * qa.y + ka.z * qa.z + ka.w * qa.w +
              kb.x * qb.x + kb.y * qb.y + kb.z * qb.z + kb.w * qb.w;
#pragma unroll
    for (int off = 32; off; off >>= 1) s += __shfl_down(s, off, 64);
    if (lane == 0) se[r] = s;
  }
  __syncthreads();

  // ---- Phase B: mask + local stats (wave 0; coalesced mask read)
  if (wave == 0) {
    const float e = mask[b * TT + t0 + lane] ? -INFINITY : se[lane];
    float m = e;
#pragma unroll
    for (int off = 32; off; off >>= 1) m = fmaxf(m, __shfl_xor(m, off, 64));
    const float msafe = (m == -INFINITY) ? 0.f : m;  // fully-masked-chunk guard
    const float w = __expf(e - msafe);
    float ss = w;
#pragma unroll
    for (int off = 32; off; off >>= 1) ss += __shfl_xor(ss, off, 64);
    sw[lane] = w;
    wbuf[b * TT + t0 + lane] = w;
    if (lane == 0) {
      mstat[b * TCH + tc] = m;
      sstat[b * TCH + tc] = ss;
    }
  }
  __syncthreads();

  // ---- Phase C: V accumulate; a[t] is an LDS broadcast (conflict-free)
  const float2* vp = (const float2*)(v + base);
  float2 acc = {0.f, 0.f};
#pragma unroll 8
  for (int t = 0; t < TC; ++t) {
    const float a = sw[t];
    const float2 vv = vp[t * 256 + tid];
    acc.x += a * vv.x;
    acc.y += a * vv.y;
  }
  ((float2*)partial)[(b * TCH + tc) * 256 + tid] = acc;
}

// ---------------------------------------------------------------------------
// Kernel 2 (combine): one block per b. Rescale-reduce the 32 chunk partials
// (2 MB, L2-resident), write context and the normalized attention row.
// ---------------------------------------------------------------------------
__global__ __launch_bounds__(256) void combine(
    const float* __restrict__ wbuf, const float* __restrict__ partial,
    const float* __restrict__ mstat, const float* __restrict__ sstat,
    float* __restrict__ ctx, float* __restrict__ attn) {
  const int b = blockIdx.x;
  const int tid = threadIdx.x;
  const int wave = tid >> 6;
  const int lane = tid & 63;

  __shared__ float scw[TCH];  // exp(m_c - m_b) / S_b

  if (wave == 0) {
    const float m = (lane < TCH) ? mstat[b * TCH + lane] : -INFINITY;
    float mb = m;
#pragma unroll
    for (int off = 32; off; off >>= 1) mb = fmaxf(mb, __shfl_xor(mb, off, 64));
    const float cw = (lane < TCH) ? __expf(m - mb) : 0.f;
    float S = (lane < TCH) ? sstat[b * TCH + lane] * cw : 0.f;
#pragma unroll
    for (int off = 32; off; off >>= 1) S += __shfl_xor(S, off, 64);
    if (lane < TCH) scw[lane] = cw / S;
  }
  __syncthreads();

  // context: thread owns float2 at d2 = tid
  const float2* p2 = (const float2*)partial;
  float2 a = {0.f, 0.f};
#pragma unroll
  for (int c = 0; c < TCH; ++c) {
    const float cwn = scw[c];
    const float2 p = p2[(b * TCH + c) * 256 + tid];
    a.x += cwn * p.x;
    a.y += cwn * p.y;
  }
  ((float2*)ctx)[b * 256 + tid] = a;

  // attention row: 2048 floats, 2 float4s per thread; chunk uniform per float4
  const float4* w4 = (const float4*)(wbuf + b * TT);
  float4* a4 = (float4*)(attn + b * TT);
#pragma unroll
  for (int i = 0; i < 2; ++i) {
    const int idx = i * 256 + tid;      // float4 index; t = idx*4
    const float cwn = scw[(idx * 4) >> 6];
    const float4 w = w4[idx];
    float4 o;
    o.x = w.x * cwn; o.y = w.y * cwn; o.z = w.z * cwn; o.w = w.w * cwn;
    a4[idx] = o;
  }
}

// ---------------------------------------------------------------------------
extern "C" void kernel_launch(void* const* d_in, const int* in_sizes, int n_in,
                              void* d_out, int out_size, void* d_ws, size_t ws_size,
                              hipStream_t stream) {
  const float* q    = (const float*)d_in[0];  // [B,D]
  const float* k    = (const float*)d_in[1];  // [B,T,D]
  const float* v    = (const float*)d_in[2];  // [B,T,D]
  const int*   mask = (const int*)d_in[3];    // [B,T], 0/1

  float* out  = (float*)d_out;
  float* ctx  = out;            // [B,D]   first output
  float* attn = out + BB * DD;  // [B,T]   second output

  float* wbuf    = (float*)d_ws;               // B*T          = 512 KB
  float* partial = wbuf + BB * TT;             // B*TCH*D      = 4 MB
  float* mstat   = partial + BB * TCH * DD;    // B*TCH        = 8 KB
  float* sstat   = mstat + BB * TCH;           // B*TCH        = 8 KB

  fused_chunk<<<dim3(BB, TCH), 256, 0, stream>>>(q, k, v, mask, wbuf, partial,
                                                 mstat, sstat);
  combine<<<BB, 256, 0, stream>>>(wbuf, partial, mstat, sstat, ctx, attn);
}

// Round 5
// 117.310 us; speedup vs baseline: 1.0281x; 1.0281x over previous
//
#include <hip/hip_runtime.h>
#include <math.h>

#define BB 64
#define TT 2048
#define DD 512
#define TCH 32            // chunks per batch row
#define TC (TT / TCH)     // 64 t per chunk

// ---------------------------------------------------------------------------
// Kernel 1 (one-pass flash chunk): block = (b, tc), 256 threads = 4 waves.
// Phase A: energy for 64 rows. Each wave: 16 rows in 4 batches of 4 -- the 4
//          shuffle-reduce chains are interleaved (independent) so DS ops run
//          at throughput, and 8 float4 loads are in flight per batch.
//          (Round-4 post-mortem: row-serial chains -> 1.5 TB/s latency-bound.)
// Phase B: local softmax stats m_c, s_c; w = exp(e - m_c) -> LDS + ws
// Phase C: acc = sum_t w[t] * V[b,t,:]  (thread owns float2 at d2 = tid)
// No cross-block communication (round-2 lesson: fences serialize the TCC).
// ---------------------------------------------------------------------------
__global__ __launch_bounds__(256) void fused_chunk(
    const float* __restrict__ q, const float* __restrict__ k,
    const float* __restrict__ v, const int* __restrict__ mask,
    float* __restrict__ wbuf,     // [B,T]  exp(e - m_c)
    float* __restrict__ partial,  // [B,TCH,D]
    float* __restrict__ mstat,    // [B,TCH]
    float* __restrict__ sstat) {  // [B,TCH]
  const int b = blockIdx.x;
  const int tc = blockIdx.y;
  const int tid = threadIdx.x;
  const int wave = tid >> 6;
  const int lane = tid & 63;

  __shared__ float se[TC];  // raw energies
  __shared__ float sw[TC];  // exp weights

  const int t0 = tc * TC;
  const long long base = ((long long)b * TT + t0) * DD;

  // ---- Phase A: energies, 4 rows in flight per wave
  const float4* qp4 = (const float4*)(q + b * DD);
  const float4 qa = qp4[lane];
  const float4 qb = qp4[lane + 64];

#pragma unroll 1
  for (int i = 0; i < 4; ++i) {
    const int r0 = wave * 16 + i * 4;
    float4 kA[4], kB[4];
#pragma unroll
    for (int j = 0; j < 4; ++j) {
      const float4* kp4 = (const float4*)(k + base + (long long)(r0 + j) * DD);
      kA[j] = kp4[lane];
      kB[j] = kp4[lane + 64];
    }
    float s[4];
#pragma unroll
    for (int j = 0; j < 4; ++j) {
      s[j] = kA[j].x * qa.x + kA[j].y * qa.y + kA[j].z * qa.z + kA[j].w * qa.w +
             kB[j].x * qb.x + kB[j].y * qb.y + kB[j].z * qb.z + kB[j].w * qb.w;
    }
#pragma unroll
    for (int off = 32; off; off >>= 1) {
#pragma unroll
      for (int j = 0; j < 4; ++j) s[j] += __shfl_down(s[j], off, 64);
    }
    if (lane == 0) {
#pragma unroll
      for (int j = 0; j < 4; ++j) se[r0 + j] = s[j];
    }
  }
  __syncthreads();

  // ---- Phase B: mask + local stats (wave 0; coalesced mask read)
  if (wave == 0) {
    const float e = mask[b * TT + t0 + lane] ? -INFINITY : se[lane];
    float m = e;
#pragma unroll
    for (int off = 32; off; off >>= 1) m = fmaxf(m, __shfl_xor(m, off, 64));
    const float msafe = (m == -INFINITY) ? 0.f : m;  // fully-masked-chunk guard
    const float w = __expf(e - msafe);
    float ss = w;
#pragma unroll
    for (int off = 32; off; off >>= 1) ss += __shfl_xor(ss, off, 64);
    sw[lane] = w;
    wbuf[b * TT + t0 + lane] = w;
    if (lane == 0) {
      mstat[b * TCH + tc] = m;
      sstat[b * TCH + tc] = ss;
    }
  }
  __syncthreads();

  // ---- Phase C: V accumulate; a[t] is an LDS broadcast (conflict-free)
  const float2* vp = (const float2*)(v + base);
  float2 acc = {0.f, 0.f};
#pragma unroll 16
  for (int t = 0; t < TC; ++t) {
    const float a = sw[t];
    const float2 vv = vp[t * 256 + tid];
    acc.x += a * vv.x;
    acc.y += a * vv.y;
  }
  ((float2*)partial)[(b * TCH + tc) * 256 + tid] = acc;
}

// ---------------------------------------------------------------------------
// Kernel 2 (combine): one block per b. Rescale-reduce the 32 chunk partials
// (4 MB, L2-resident), write context and the normalized attention row.
// ---------------------------------------------------------------------------
__global__ __launch_bounds__(256) void combine(
    const float* __restrict__ wbuf, const float* __restrict__ partial,
    const float* __restrict__ mstat, const float* __restrict__ sstat,
    float* __restrict__ ctx, float* __restrict__ attn) {
  const int b = blockIdx.x;
  const int tid = threadIdx.x;
  const int wave = tid >> 6;
  const int lane = tid & 63;

  __shared__ float scw[TCH];  // exp(m_c - m_b) / S_b

  if (wave == 0) {
    const float m = (lane < TCH) ? mstat[b * TCH + lane] : -INFINITY;
    float mb = m;
#pragma unroll
    for (int off = 32; off; off >>= 1) mb = fmaxf(mb, __shfl_xor(mb, off, 64));
    const float cw = (lane < TCH) ? __expf(m - mb) : 0.f;
    float S = (lane < TCH) ? sstat[b * TCH + lane] * cw : 0.f;
#pragma unroll
    for (int off = 32; off; off >>= 1) S += __shfl_xor(S, off, 64);
    if (lane < TCH) scw[lane] = cw / S;
  }
  __syncthreads();

  // context: thread owns float2 at d2 = tid
  const float2* p2 = (const float2*)partial;
  float2 a = {0.f, 0.f};
#pragma unroll
  for (int c = 0; c < TCH; ++c) {
    const float cwn = scw[c];
    const float2 p = p2[(b * TCH + c) * 256 + tid];
    a.x += cwn * p.x;
    a.y += cwn * p.y;
  }
  ((float2*)ctx)[b * 256 + tid] = a;

  // attention row: 2048 floats, 2 float4s per thread; chunk uniform per float4
  const float4* w4 = (const float4*)(wbuf + b * TT);
  float4* a4 = (float4*)(attn + b * TT);
#pragma unroll
  for (int i = 0; i < 2; ++i) {
    const int idx = i * 256 + tid;      // float4 index; t = idx*4
    const float cwn = scw[(idx * 4) >> 6];
    const float4 w = w4[idx];
    float4 o;
    o.x = w.x * cwn; o.y = w.y * cwn; o.z = w.z * cwn; o.w = w.w * cwn;
    a4[idx] = o;
  }
}

// ---------------------------------------------------------------------------
extern "C" void kernel_launch(void* const* d_in, const int* in_sizes, int n_in,
                              void* d_out, int out_size, void* d_ws, size_t ws_size,
                              hipStream_t stream) {
  const float* q    = (const float*)d_in[0];  // [B,D]
  const float* k    = (const float*)d_in[1];  // [B,T,D]
  const float* v    = (const float*)d_in[2];  // [B,T,D]
  const int*   mask = (const int*)d_in[3];    // [B,T], 0/1

  float* out  = (float*)d_out;
  float* ctx  = out;            // [B,D]   first output
  float* attn = out + BB * DD;  // [B,T]   second output

  float* wbuf    = (float*)d_ws;               // B*T          = 512 KB
  float* partial = wbuf + BB * TT;             // B*TCH*D      = 4 MB
  float* mstat   = partial + BB * TCH * DD;    // B*TCH        = 8 KB
  float* sstat   = mstat + BB * TCH;           // B*TCH        = 8 KB

  fused_chunk<<<dim3(BB, TCH), 256, 0, stream>>>(q, k, v, mask, wbuf, partial,
                                                 mstat, sstat);
  combine<<<BB, 256, 0, stream>>>(wbuf, partial, mstat, sstat, ctx, attn);
}

// Round 6
// 111.438 us; speedup vs baseline: 1.0823x; 1.0527x over previous
//
#include <hip/hip_runtime.h>
#include <math.h>

#define BB 64
#define TT 2048
#define DD 512
#define TCH 32            // chunks per batch row
#define TC (TT / TCH)     // 64 t per chunk

// ---------------------------------------------------------------------------
// Kernel 1 (one-pass flash chunk): block = (b, tc), 256 threads = 4 waves.
//
// Round-5 post-mortem: the per-row 6-deep shuffle chain inside Phase A's loop
// serialized the K stream (1.5 TB/s, VALUBusy 3%). Fix: Phase A is now a pure
// stream -- wave-per-row coalesced loads, lane keeps an 8-elem partial dot,
// ONE ds_write per row, no cross-lane ops in the loop. Phase A2 reduces the
// 64x64 lane-partial matrix from LDS once per block.
// ---------------------------------------------------------------------------
__global__ __launch_bounds__(256) void fused_chunk(
    const float* __restrict__ q, const float* __restrict__ k,
    const float* __restrict__ v, const int* __restrict__ mask,
    float* __restrict__ wbuf,     // [B,T]  exp(e - m_c)
    float* __restrict__ partial,  // [B,TCH,D]
    float* __restrict__ mstat,    // [B,TCH]
    float* __restrict__ sstat) {  // [B,TCH]
  const int b = blockIdx.x;
  const int tc = blockIdx.y;
  const int tid = threadIdx.x;
  const int wave = tid >> 6;
  const int lane = tid & 63;

  // sep[r][0..63] = lane partials; sep[r][64] = reduced row energy.
  // Stride 68 floats: 16B-aligned rows (68*4=272=16*17), read-phase banks <=4-way.
  __shared__ float sep[TC][68];
  __shared__ float sw[TC];

  const int t0 = tc * TC;
  const long long base = ((long long)b * TT + t0) * DD;

  // ---- Phase A: K stream; each wave 16 rows, independent iterations
  const float4* qp4 = (const float4*)(q + b * DD);
  const float4 qa = qp4[lane];
  const float4 qb = qp4[lane + 64];

#pragma unroll
  for (int i = 0; i < 16; ++i) {
    const int r = wave * 16 + i;
    const float4* kp4 = (const float4*)(k + base + (long long)r * DD);
    const float4 ka = kp4[lane];
    const float4 kb = kp4[lane + 64];
    sep[r][lane] =
        ka.x * qa.x + ka.y * qa.y + ka.z * qa.z + ka.w * qa.w +
        kb.x * qb.x + kb.y * qb.y + kb.z * qb.z + kb.w * qb.w;
  }
  __syncthreads();

  // ---- Phase A2: row sums. Thread (r = tid/4, qt = tid%4) sums 16 floats
  // (4x ds_read_b128), then 2-step shuffle across the 4-thread group.
  {
    const int r = tid >> 2;
    const int qt = tid & 3;
    const float4* p4 = (const float4*)&sep[r][qt * 16];
    float4 s0 = p4[0], s1 = p4[1], s2 = p4[2], s3 = p4[3];
    float s = (s0.x + s0.y + s0.z + s0.w) + (s1.x + s1.y + s1.z + s1.w) +
              (s2.x + s2.y + s2.z + s2.w) + (s3.x + s3.y + s3.z + s3.w);
    s += __shfl_xor(s, 1, 64);
    s += __shfl_xor(s, 2, 64);
    if (qt == 0) sep[r][64] = s;
  }
  __syncthreads();

  // ---- Phase B: mask + local stats (wave 0; once per block)
  if (wave == 0) {
    const float e = mask[b * TT + t0 + lane] ? -INFINITY : sep[lane][64];
    float m = e;
#pragma unroll
    for (int off = 32; off; off >>= 1) m = fmaxf(m, __shfl_xor(m, off, 64));
    const float msafe = (m == -INFINITY) ? 0.f : m;  // fully-masked-chunk guard
    const float w = __expf(e - msafe);
    float ss = w;
#pragma unroll
    for (int off = 32; off; off >>= 1) ss += __shfl_xor(ss, off, 64);
    sw[lane] = w;
    wbuf[b * TT + t0 + lane] = w;
    if (lane == 0) {
      mstat[b * TCH + tc] = m;
      sstat[b * TCH + tc] = ss;
    }
  }
  __syncthreads();

  // ---- Phase C: V stream; a[t] is an LDS broadcast (conflict-free)
  const float2* vp = (const float2*)(v + base);
  float2 acc = {0.f, 0.f};
#pragma unroll 16
  for (int t = 0; t < TC; ++t) {
    const float a = sw[t];
    const float2 vv = vp[t * 256 + tid];
    acc.x += a * vv.x;
    acc.y += a * vv.y;
  }
  ((float2*)partial)[(b * TCH + tc) * 256 + tid] = acc;
}

// ---------------------------------------------------------------------------
// Kernel 2 (combine): one block per b. Rescale-reduce the 32 chunk partials
// (4 MB, L2-resident), write context and the normalized attention row.
// (Numerically validated in rounds 4-5: absmax 9.8e-4.)
// ---------------------------------------------------------------------------
__global__ __launch_bounds__(256) void combine(
    const float* __restrict__ wbuf, const float* __restrict__ partial,
    const float* __restrict__ mstat, const float* __restrict__ sstat,
    float* __restrict__ ctx, float* __restrict__ attn) {
  const int b = blockIdx.x;
  const int tid = threadIdx.x;
  const int wave = tid >> 6;
  const int lane = tid & 63;

  __shared__ float scw[TCH];  // exp(m_c - m_b) / S_b

  if (wave == 0) {
    const float m = (lane < TCH) ? mstat[b * TCH + lane] : -INFINITY;
    float mb = m;
#pragma unroll
    for (int off = 32; off; off >>= 1) mb = fmaxf(mb, __shfl_xor(mb, off, 64));
    const float cw = (lane < TCH) ? __expf(m - mb) : 0.f;
    float S = (lane < TCH) ? sstat[b * TCH + lane] * cw : 0.f;
#pragma unroll
    for (int off = 32; off; off >>= 1) S += __shfl_xor(S, off, 64);
    if (lane < TCH) scw[lane] = cw / S;
  }
  __syncthreads();

  // context: thread owns float2 at d2 = tid
  const float2* p2 = (const float2*)partial;
  float2 a = {0.f, 0.f};
#pragma unroll
  for (int c = 0; c < TCH; ++c) {
    const float cwn = scw[c];
    const float2 p = p2[(b * TCH + c) * 256 + tid];
    a.x += cwn * p.x;
    a.y += cwn * p.y;
  }
  ((float2*)ctx)[b * 256 + tid] = a;

  // attention row: 2048 floats, 2 float4s per thread; chunk uniform per float4
  const float4* w4 = (const float4*)(wbuf + b * TT);
  float4* a4 = (float4*)(attn + b * TT);
#pragma unroll
  for (int i = 0; i < 2; ++i) {
    const int idx = i * 256 + tid;      // float4 index; t = idx*4
    const float cwn = scw[(idx * 4) >> 6];
    const float4 w = w4[idx];
    float4 o;
    o.x = w.x * cwn; o.y = w.y * cwn; o.z = w.z * cwn; o.w = w.w * cwn;
    a4[idx] = o;
  }
}

// ---------------------------------------------------------------------------
extern "C" void kernel_launch(void* const* d_in, const int* in_sizes, int n_in,
                              void* d_out, int out_size, void* d_ws, size_t ws_size,
                              hipStream_t stream) {
  const float* q    = (const float*)d_in[0];  // [B,D]
  const float* k    = (const float*)d_in[1];  // [B,T,D]
  const float* v    = (const float*)d_in[2];  // [B,T,D]
  const int*   mask = (const int*)d_in[3];    // [B,T], 0/1

  float* out  = (float*)d_out;
  float* ctx  = out;            // [B,D]   first output
  float* attn = out + BB * DD;  // [B,T]   second output

  float* wbuf    = (float*)d_ws;               // B*T          = 512 KB
  float* partial = wbuf + BB * TT;             // B*TCH*D      = 4 MB
  float* mstat   = partial + BB * TCH * DD;    // B*TCH        = 8 KB
  float* sstat   = mstat + BB * TCH;           // B*TCH        = 8 KB

  fused_chunk<<<dim3(BB, TCH), 256, 0, stream>>>(q, k, v, mask, wbuf, partial,
                                                 mstat, sstat);
  combine<<<BB, 256, 0, stream>>>(wbuf, partial, mstat, sstat, ctx, attn);
}

// Round 7
// 103.250 us; speedup vs baseline: 1.1681x; 1.0793x over previous
//
#include <hip/hip_runtime.h>
#include <math.h>

#define BB 64
#define TT 2048
#define DD 512
#define TCH 32            // t-chunks in PV pass (round 3 proven at 16; 32 = 2x TLP)
#define TC (TT / TCH)     // 64 t per chunk

// ---------------------------------------------------------------------------
// Kernel 1: energy[b,t] = dot(key[b,t,:], query[b,:]); masked -> -inf
// 256 threads = 4 waves per block; each wave computes one (b,t) row.
// 8192 blocks -> 32 waves/CU: the per-row shuffle chain hides under TLP.
// (Round-6 lesson: streaming rate on gfx950 comes from wave count with
//  trivial loops, not intra-block ILP -- the compiler serializes loads.)
// ---------------------------------------------------------------------------
__global__ __launch_bounds__(256) void energy_kernel(
    const float* __restrict__ q, const float* __restrict__ k,
    const int* __restrict__ mask, float* __restrict__ energy) {
  const int wave = threadIdx.x >> 6;
  const int lane = threadIdx.x & 63;
  const long long row = (long long)blockIdx.x * 4 + wave;  // b*TT + t
  const int b = (int)(row >> 11);

  const float4* kp4 = (const float4*)(k + row * DD);
  const float4* qp4 = (const float4*)(q + (long long)b * DD);

  float4 ka = kp4[lane];
  float4 kb = kp4[lane + 64];
  float4 qa = qp4[lane];
  float4 qb = qp4[lane + 64];

  float s = ka.x * qa.x + ka.y * qa.y + ka.z * qa.z + ka.w * qa.w +
            kb.x * qb.x + kb.y * qb.y + kb.z * qb.z + kb.w * qb.w;

#pragma unroll
  for (int off = 32; off; off >>= 1) s += __shfl_down(s, off, 64);

  if (lane == 0) {
    energy[row] = mask[row] ? -INFINITY : s;
  }
}

// ---------------------------------------------------------------------------
// Kernel 2: per-b softmax stats recomputed per block (energy row is
// L2-resident; 6% of the block's stream bytes) + attention write (tc==0)
// + PV chunk partial. No cross-block comm (round-2: fences serialize TCC).
// Grid: (BB, TCH) x 128 threads. Thread tid owns float4 at d = 4*tid.
// ---------------------------------------------------------------------------
__global__ __launch_bounds__(128) void pv_fused(
    const float* __restrict__ energy, const float* __restrict__ v,
    float* __restrict__ attn, float* __restrict__ partial) {
  const int b = blockIdx.x;
  const int tc = blockIdx.y;
  const int tid = threadIdx.x;  // 0..127
  const int wave = tid >> 6;
  const int lane = tid & 63;

  __shared__ float sred[2];
  __shared__ float sa[TC];

  // ---- softmax stats over energy[b, :]  (2048 floats, 4x float4 per thread)
  const float4* e4 = (const float4*)(energy + b * TT);
  float4 ev[4];
  float m = -INFINITY;
#pragma unroll
  for (int i = 0; i < 4; i++) {
    ev[i] = e4[i * 128 + tid];
    m = fmaxf(m, fmaxf(fmaxf(ev[i].x, ev[i].y), fmaxf(ev[i].z, ev[i].w)));
  }
#pragma unroll
  for (int off = 32; off; off >>= 1) m = fmaxf(m, __shfl_xor(m, off, 64));
  if (lane == 0) sred[wave] = m;
  __syncthreads();
  m = fmaxf(sred[0], sred[1]);
  __syncthreads();  // sred reused for the sum below

  float ssum = 0.f;
#pragma unroll
  for (int i = 0; i < 4; i++) {
    ev[i].x = __expf(ev[i].x - m);
    ev[i].y = __expf(ev[i].y - m);
    ev[i].z = __expf(ev[i].z - m);
    ev[i].w = __expf(ev[i].w - m);
    ssum += ev[i].x + ev[i].y + ev[i].z + ev[i].w;
  }
#pragma unroll
  for (int off = 32; off; off >>= 1) ssum += __shfl_xor(ssum, off, 64);
  if (lane == 0) sred[wave] = ssum;
  __syncthreads();
  ssum = sred[0] + sred[1];
  const float inv = 1.0f / ssum;

  // ---- attention output (one writer block per b; regs already hold the row)
  if (tc == 0) {
    float4* a4 = (float4*)(attn + b * TT);
#pragma unroll
    for (int i = 0; i < 4; i++) {
      float4 o;
      o.x = ev[i].x * inv; o.y = ev[i].y * inv;
      o.z = ev[i].z * inv; o.w = ev[i].w * inv;
      a4[i * 128 + tid] = o;
    }
  }

  // ---- chunk weights into LDS (first TC threads)
  const float* ep = energy + b * TT + tc * TC;
  if (tid < TC) sa[tid] = __expf(ep[tid] - m) * inv;
  __syncthreads();

  // ---- PV chunk: pure V stream; a[t] is an LDS broadcast (conflict-free)
  const float4* vp = (const float4*)(v + ((long long)b * TT + (long long)tc * TC) * DD);
  float4 acc = {0.f, 0.f, 0.f, 0.f};
#pragma unroll 8
  for (int t = 0; t < TC; t++) {
    const float a = sa[t];
    const float4 vv = vp[t * 128 + tid];
    acc.x += a * vv.x;
    acc.y += a * vv.y;
    acc.z += a * vv.z;
    acc.w += a * vv.w;
  }
  ((float4*)partial)[(b * TCH + tc) * 128 + tid] = acc;
}

// ---------------------------------------------------------------------------
// Kernel 3: context[b,d] = sum_tc partial[b,tc,d]  (4 MB, L2-resident)
// One thread per float4 of context: B*D/4 = 8192 threads = 32 blocks.
// ---------------------------------------------------------------------------
__global__ __launch_bounds__(256) void pv_reduce(
    const float* __restrict__ partial, float* __restrict__ ctx) {
  const int i = blockIdx.x * 256 + threadIdx.x;  // over B*128 float4s
  const int b = i >> 7;
  const int d4 = i & 127;
  const float4* p4 = (const float4*)partial;
  float4 s = {0.f, 0.f, 0.f, 0.f};
#pragma unroll
  for (int tc = 0; tc < TCH; tc++) {
    const float4 p = p4[(b * TCH + tc) * 128 + d4];
    s.x += p.x; s.y += p.y; s.z += p.z; s.w += p.w;
  }
  ((float4*)ctx)[i] = s;
}

// ---------------------------------------------------------------------------
extern "C" void kernel_launch(void* const* d_in, const int* in_sizes, int n_in,
                              void* d_out, int out_size, void* d_ws, size_t ws_size,
                              hipStream_t stream) {
  const float* q    = (const float*)d_in[0];  // [B,D]
  const float* k    = (const float*)d_in[1];  // [B,T,D]
  const float* v    = (const float*)d_in[2];  // [B,T,D]
  const int*   mask = (const int*)d_in[3];    // [B,T], 0/1

  float* out  = (float*)d_out;
  float* ctx  = out;            // [B,D]   first output
  float* attn = out + BB * DD;  // [B,T]   second output

  float* energy  = (float*)d_ws;        // B*T floats   = 512 KB
  float* partial = energy + BB * TT;    // B*TCH*D fl   = 4 MB

  energy_kernel<<<BB * TT / 4, 256, 0, stream>>>(q, k, mask, energy);
  pv_fused<<<dim3(BB, TCH), 128, 0, stream>>>(energy, v, attn, partial);
  pv_reduce<<<BB * DD / 4 / 256, 256, 0, stream>>>(partial, ctx);
}

// Round 8
// 103.239 us; speedup vs baseline: 1.1682x; 1.0001x over previous
//
#include <hip/hip_runtime.h>
#include <math.h>

#define BB 64
#define TT 2048
#define DD 512
#define NCH 16            // PV blocks per b (each covers 128 rows, two 64-row halves)
#define NPART 32          // partials per b (2 per block)

// ---------------------------------------------------------------------------
// Kernel 1: energy[b,t] = dot(key[b,t,:], query[b,:]); masked -> -inf
// 256 threads = 4 waves per block; each wave computes one (b,t) row.
// 8192 blocks -> full TLP; per-row shuffle chain hides under wave count.
// Proven at ~6.7 TB/s (rounds 1/3/7).
// ---------------------------------------------------------------------------
__global__ __launch_bounds__(256) void energy_kernel(
    const float* __restrict__ q, const float* __restrict__ k,
    const int* __restrict__ mask, float* __restrict__ energy) {
  const int wave = threadIdx.x >> 6;
  const int lane = threadIdx.x & 63;
  const long long row = (long long)blockIdx.x * 4 + wave;  // b*TT + t
  const int b = (int)(row >> 11);

  const float4* kp4 = (const float4*)(k + row * DD);
  const float4* qp4 = (const float4*)(q + (long long)b * DD);

  float4 ka = kp4[lane];
  float4 kb = kp4[lane + 64];
  float4 qa = qp4[lane];
  float4 qb = qp4[lane + 64];

  float s = ka.x * qa.x + ka.y * qa.y + ka.z * qa.z + ka.w * qa.w +
            kb.x * qb.x + kb.y * qb.y + kb.z * qb.z + kb.w * qb.w;

#pragma unroll
  for (int off = 32; off; off >>= 1) s += __shfl_down(s, off, 64);

  if (lane == 0) {
    energy[row] = mask[row] ? -INFINITY : s;
  }
}

// ---------------------------------------------------------------------------
// Kernel 2: dual-half PV. Grid (BB, NCH) x 256 threads. One softmax-stat
// prologue per block (1024 total, same as round-3 best); threads 0-127
// stream rows [c*128, c*128+64), threads 128-255 stream [c*128+64, c*128+128),
// each lane owning a float4 of D -> 16 waves/CU on the V stream at round-3's
// prologue count. (Round-7 post-mortem: TCH=32 doubled prologues and lost;
// round-3 had only 8 waves/CU on the stream.)
// ---------------------------------------------------------------------------
__global__ __launch_bounds__(256) void pv_fused(
    const float* __restrict__ energy, const float* __restrict__ v,
    float* __restrict__ attn, float* __restrict__ partial) {
  const int b = blockIdx.x;
  const int c = blockIdx.y;       // 128-row chunk index
  const int tid = threadIdx.x;    // 0..255
  const int wave = tid >> 6;
  const int lane = tid & 63;
  const int half = tid >> 7;      // 0 or 1
  const int htid = tid & 127;     // lane within half; owns float4 at d = 4*htid

  __shared__ float sred[4];
  __shared__ float sa[128];

  // ---- softmax stats over energy[b,:] (2048 floats, 2 float4 per thread)
  const float4* e4 = (const float4*)(energy + b * TT);
  float4 ev[2];
  float m = -INFINITY;
#pragma unroll
  for (int i = 0; i < 2; i++) {
    ev[i] = e4[i * 256 + tid];
    m = fmaxf(m, fmaxf(fmaxf(ev[i].x, ev[i].y), fmaxf(ev[i].z, ev[i].w)));
  }
#pragma unroll
  for (int off = 32; off; off >>= 1) m = fmaxf(m, __shfl_xor(m, off, 64));
  if (lane == 0) sred[wave] = m;
  __syncthreads();
  m = fmaxf(fmaxf(sred[0], sred[1]), fmaxf(sred[2], sred[3]));
  __syncthreads();  // sred reused below

  float ssum = 0.f;
#pragma unroll
  for (int i = 0; i < 2; i++) {
    ev[i].x = __expf(ev[i].x - m);
    ev[i].y = __expf(ev[i].y - m);
    ev[i].z = __expf(ev[i].z - m);
    ev[i].w = __expf(ev[i].w - m);
    ssum += ev[i].x + ev[i].y + ev[i].z + ev[i].w;
  }
#pragma unroll
  for (int off = 32; off; off >>= 1) ssum += __shfl_xor(ssum, off, 64);
  if (lane == 0) sred[wave] = ssum;
  __syncthreads();
  ssum = (sred[0] + sred[1]) + (sred[2] + sred[3]);
  const float inv = 1.0f / ssum;

  // ---- attention output (one writer block per b; regs already hold exp row)
  if (c == 0) {
    float4* a4 = (float4*)(attn + b * TT);
#pragma unroll
    for (int i = 0; i < 2; i++) {
      float4 o;
      o.x = ev[i].x * inv; o.y = ev[i].y * inv;
      o.z = ev[i].z * inv; o.w = ev[i].w * inv;
      a4[i * 256 + tid] = o;
    }
  }

  // ---- chunk weights for this block's 128 rows (coalesced 512B read)
  if (tid < 128) {
    sa[tid] = __expf(energy[b * TT + c * 128 + tid] - m) * inv;
  }
  __syncthreads();

  // ---- V stream: half h covers rows [c*128 + h*64, +64)
  const float4* vp =
      (const float4*)(v + ((long long)b * TT + c * 128 + half * 64) * DD);
  const float* saw = sa + half * 64;
  float4 acc = {0.f, 0.f, 0.f, 0.f};
#pragma unroll 8
  for (int t = 0; t < 64; t++) {
    const float a = saw[t];                 // LDS broadcast, conflict-free
    const float4 vv = vp[t * 128 + htid];   // 16B/lane coalesced
    acc.x += a * vv.x;
    acc.y += a * vv.y;
    acc.z += a * vv.z;
    acc.w += a * vv.w;
  }
  ((float4*)partial)[((b * NCH + c) * 2 + half) * 128 + htid] = acc;
}

// ---------------------------------------------------------------------------
// Kernel 3: context[b,d] = sum over 32 partials (4 MB, L2-resident).
// One thread per float4 of context: B*D/4 = 8192 threads = 32 blocks.
// ---------------------------------------------------------------------------
__global__ __launch_bounds__(256) void pv_reduce(
    const float* __restrict__ partial, float* __restrict__ ctx) {
  const int i = blockIdx.x * 256 + threadIdx.x;  // over B*128 float4s
  const int b = i >> 7;
  const int d4 = i & 127;
  const float4* p4 = (const float4*)partial;
  float4 s = {0.f, 0.f, 0.f, 0.f};
#pragma unroll
  for (int p = 0; p < NPART; p++) {
    const float4 pv = p4[(b * NPART + p) * 128 + d4];
    s.x += pv.x; s.y += pv.y; s.z += pv.z; s.w += pv.w;
  }
  ((float4*)ctx)[i] = s;
}

// ---------------------------------------------------------------------------
extern "C" void kernel_launch(void* const* d_in, const int* in_sizes, int n_in,
                              void* d_out, int out_size, void* d_ws, size_t ws_size,
                              hipStream_t stream) {
  const float* q    = (const float*)d_in[0];  // [B,D]
  const float* k    = (const float*)d_in[1];  // [B,T,D]
  const float* v    = (const float*)d_in[2];  // [B,T,D]
  const int*   mask = (const int*)d_in[3];    // [B,T], 0/1

  float* out  = (float*)d_out;
  float* ctx  = out;            // [B,D]   first output
  float* attn = out + BB * DD;  // [B,T]   second output

  float* energy  = (float*)d_ws;        // B*T floats     = 512 KB
  float* partial = energy + BB * TT;    // B*NPART*D fl   = 4 MB

  energy_kernel<<<BB * TT / 4, 256, 0, stream>>>(q, k, mask, energy);
  pv_fused<<<dim3(BB, NCH), 256, 0, stream>>>(energy, v, attn, partial);
  pv_reduce<<<BB * DD / 4 / 256, 256, 0, stream>>>(partial, ctx);
}